// Round 2
// baseline (215.769 us; speedup 1.0000x reference)
//
#include <hip/hip_runtime.h>
#include <math.h>

// QCCNN fused kernel for MI355X (gfx950) — Round 2: maximally-defensive variant.
// One thread per image. No cross-lane ops, no vector loads of x, no early
// returns, every output element written unconditionally by exactly one thread.
//
// Pipeline per image b:
//   9 overlapping 4x4 patches -> normalize -> 4-qubit state (16 real amps)
//   -> per quantum kernel k (4 of them): 4 single-qubit rotations applied as
//      butterflies (CNOT chain folded into measurement permutation PERM)
//   -> X,Y,Z expectations -> leaky -> fc1 accumulate (h[32])
//   -> leaky -> fc2 -> out[b*3 .. b*3+2]

#define QC_EPS 1e-12f

__device__ __forceinline__ float leakyf(float v) { return v >= 0.0f ? v : 0.1f * v; }

__global__ __launch_bounds__(256) void qccnn_fused(
    const float* __restrict__ x,     // (B,1,8,8)
    const float* __restrict__ qw,    // (4,4,3)
    const float* __restrict__ w1,    // (32,108)
    const float* __restrict__ b1,    // (32,)
    const float* __restrict__ w2,    // (3,32)
    const float* __restrict__ b2,    // (3,)
    float* __restrict__ out,         // (B,3)
    int Bsz)
{
    __shared__ float s_w1[108][32];   // transposed: s_w1[f][o] = w1[o*108+f]
    __shared__ float s_qm[4][4][8];   // [kernel][qubit][m00r,m00i,m01r,m01i,m10r,m10i,m11r,m11i]
    __shared__ float s_b1[32];
    __shared__ float s_w2[3][32];
    __shared__ float s_b2[3];

    const int tid = threadIdx.x;

    // ---- cooperative LDS setup (all writes precede the single barrier) ----
    for (int idx = tid; idx < 32 * 108; idx += 256) {
        const int o = idx / 108, f = idx % 108;
        s_w1[f][o] = w1[idx];
    }
    if (tid < 32) s_b1[tid] = b1[tid];
    if (tid < 96) s_w2[tid / 32][tid % 32] = w2[tid];
    if (tid < 3)  s_b2[tid] = b2[tid];
    if (tid < 16) {
        const int k = tid >> 2, q = tid & 3;
        const float phi = qw[(k * 4 + q) * 3 + 0];
        const float th  = qw[(k * 4 + q) * 3 + 1];
        const float om  = qw[(k * 4 + q) * 3 + 2];
        float c, s, ca, sa, cb, sb;
        sincosf(0.5f * th, &s, &c);
        sincosf(0.5f * (phi + om), &sa, &ca);
        sincosf(0.5f * (phi - om), &sb, &cb);
        float* M = &s_qm[k][q][0];
        // m00 = exp(-i(phi+om)/2)*c ; m01 = -exp(+i(phi-om)/2)*s
        // m10 = exp(-i(phi-om)/2)*s ; m11 = exp(+i(phi+om)/2)*c
        M[0] =  ca * c;  M[1] = -sa * c;
        M[2] = -cb * s;  M[3] = -sb * s;
        M[4] =  cb * s;  M[5] = -sb * s;
        M[6] =  ca * c;  M[7] =  sa * c;
    }
    __syncthreads();

    const int b = blockIdx.x * 256 + tid;
    if (b < Bsz) {
        const float* xb = x + (size_t)b * 64;

        float h[32];
#pragma unroll
        for (int o = 0; o < 32; ++o) h[o] = 0.0f;

        // CNOT chain (0,1)(1,2)(2,3)(3,0) folded into measurement indexing:
        // s_final[i] = s_mid[PERM[i]]  (re-verified index-by-index)
        constexpr int PERM[16] = {0, 13, 3, 14, 6, 11, 5, 8, 12, 1, 15, 2, 10, 7, 9, 4};

#pragma unroll
        for (int pi = 0; pi < 3; ++pi) {
#pragma unroll
            for (int pj = 0; pj < 3; ++pj) {
                // ---- extract + normalize 4x4 patch (scalar, L1-cached) ----
                float p[16];
                const float* pr = xb + pi * 16 + pj * 2;
#pragma unroll
                for (int r = 0; r < 4; ++r) {
#pragma unroll
                    for (int cidx = 0; cidx < 4; ++cidx)
                        p[r * 4 + cidx] = pr[r * 8 + cidx];
                }
                float ssum = 0.0f;
#pragma unroll
                for (int l = 0; l < 16; ++l) ssum += p[l] * p[l];
                const float inv = 1.0f / (sqrtf(ssum) + QC_EPS);
#pragma unroll
                for (int l = 0; l < 16; ++l) p[l] *= inv;

#pragma unroll
                for (int k = 0; k < 4; ++k) {
                    float sr[16], si[16];

                    // gate on qubit 3 (bit mask 1), real input
                    {
                        const float* M = &s_qm[k][3][0];
                        const float m00r = M[0], m00i = M[1], m01r = M[2], m01i = M[3];
                        const float m10r = M[4], m10i = M[5], m11r = M[6], m11i = M[7];
#pragma unroll
                        for (int t = 0; t < 8; ++t) {
                            const float a0 = p[2 * t], a1 = p[2 * t + 1];
                            sr[2 * t]     = m00r * a0 + m01r * a1;
                            si[2 * t]     = m00i * a0 + m01i * a1;
                            sr[2 * t + 1] = m10r * a0 + m11r * a1;
                            si[2 * t + 1] = m10i * a0 + m11i * a1;
                        }
                    }

                    // gates on qubits 2,1,0 (masks 2,4,8), complex state
#pragma unroll
                    for (int g = 0; g < 3; ++g) {
                        const int qq = (g == 0) ? 2 : ((g == 1) ? 1 : 0);
                        const int m  = (g == 0) ? 2 : ((g == 1) ? 4 : 8);
                        const float* M = &s_qm[k][qq][0];
                        const float m00r = M[0], m00i = M[1], m01r = M[2], m01i = M[3];
                        const float m10r = M[4], m10i = M[5], m11r = M[6], m11i = M[7];
#pragma unroll
                        for (int i0 = 0; i0 < 16; ++i0) {
                            if (i0 & m) continue;
                            const int i1 = i0 | m;
                            const float t0r = sr[i0], t0i = si[i0];
                            const float t1r = sr[i1], t1i = si[i1];
                            sr[i0] = m00r * t0r - m00i * t0i + m01r * t1r - m01i * t1i;
                            si[i0] = m00r * t0i + m00i * t0r + m01r * t1i + m01i * t1r;
                            sr[i1] = m10r * t0r - m10i * t0i + m11r * t1r - m11i * t1i;
                            si[i1] = m10r * t0i + m10i * t0r + m11r * t1i + m11i * t1r;
                        }
                    }

                    // ---- measurement (CNOT perm folded in) ----
                    float abr = 0.0f, abi = 0.0f, zz = 0.0f;
#pragma unroll
                    for (int jj = 0; jj < 8; ++jj) {
                        const int ia = PERM[jj], ib = PERM[8 + jj];
                        const float ar = sr[ia], ai = si[ia];
                        const float br = sr[ib], bi = si[ib];
                        abr += ar * br + ai * bi;
                        abi += ar * bi - ai * br;
                        zz  += (ar * ar + ai * ai) - (br * br + bi * bi);
                    }

                    // ---- leaky + fc1 accumulate (s_w1 reads are wave-uniform broadcasts) ----
                    const float f0 = leakyf(2.0f * abr);
                    const float f1 = leakyf(2.0f * abi);
                    const float f2 = leakyf(zz);
                    const int fbase = k * 27 + pi * 3 + pj;   // (k*3+comp)*9 + pi*3+pj
#pragma unroll
                    for (int comp = 0; comp < 3; ++comp) {
                        const float lf = (comp == 0) ? f0 : ((comp == 1) ? f1 : f2);
                        const int f = fbase + comp * 9;
#pragma unroll
                        for (int o4 = 0; o4 < 8; ++o4) {
                            const float4 wv = *reinterpret_cast<const float4*>(&s_w1[f][o4 * 4]);
                            h[o4 * 4 + 0] += wv.x * lf;
                            h[o4 * 4 + 1] += wv.y * lf;
                            h[o4 * 4 + 2] += wv.z * lf;
                            h[o4 * 4 + 3] += wv.w * lf;
                        }
                    }
                }
            }
        }

        // ---- fc1 bias + leaky, fc2 ----
        float o0 = s_b2[0], o1 = s_b2[1], o2 = s_b2[2];
#pragma unroll
        for (int o = 0; o < 32; ++o) {
            const float hv = leakyf(h[o] + s_b1[o]);
            o0 += s_w2[0][o] * hv;
            o1 += s_w2[1][o] * hv;
            o2 += s_w2[2][o] * hv;
        }
        float* ob = out + (size_t)b * 3;
        ob[0] = o0; ob[1] = o1; ob[2] = o2;
    }
}

extern "C" void kernel_launch(void* const* d_in, const int* in_sizes, int n_in,
                              void* d_out, int out_size, void* d_ws, size_t ws_size,
                              hipStream_t stream) {
    (void)n_in; (void)out_size; (void)d_ws; (void)ws_size;
    const float* x  = (const float*)d_in[0];
    const float* qw = (const float*)d_in[1];
    const float* w1 = (const float*)d_in[2];
    const float* b1 = (const float*)d_in[3];
    const float* w2 = (const float*)d_in[4];
    const float* b2 = (const float*)d_in[5];
    float* out = (float*)d_out;

    const int Bsz = in_sizes[0] / 64;          // x is (B,1,8,8)
    const int threads = 256;
    const int blocks = (Bsz + threads - 1) / threads;

    qccnn_fused<<<blocks, threads, 0, stream>>>(x, qw, w1, b1, w2, b2, out, Bsz);
}